// Round 2
// baseline (392.205 us; speedup 1.0000x reference)
//
#include <hip/hip_runtime.h>
#include <stdint.h>

typedef short v8s __attribute__((ext_vector_type(8)));
typedef short v4s __attribute__((ext_vector_type(4)));
typedef float v4f __attribute__((ext_vector_type(4)));
typedef unsigned int u32;
typedef unsigned short us;

#define LOG2E 1.44269504088896340736f

__device__ __forceinline__ u32 f2u(float x) {
  union { float f; u32 u; } t; t.f = x; return t.u;
}

__device__ __forceinline__ unsigned short bfr(float x) {
  u32 u = f2u(x);
  u32 r = u + 0x7FFFu + ((u >> 16) & 1u);
  return (unsigned short)(r >> 16);
}

__device__ __forceinline__ void async16(const void* g, void* l) {
  __builtin_amdgcn_global_load_lds(
      (const __attribute__((address_space(1))) u32*)g,
      (__attribute__((address_space(3))) u32*)l, 16, 0, 0);
}

#if __has_builtin(__builtin_amdgcn_mfma_f32_16x16x16bf16_1k)
#define MFMA_K16(A, B, C) __builtin_amdgcn_mfma_f32_16x16x16bf16_1k((A), (B), (C), 0, 0, 0)
#elif __has_builtin(__builtin_amdgcn_mfma_f32_16x16x16_bf16)
#define MFMA_K16(A, B, C) __builtin_amdgcn_mfma_f32_16x16x16_bf16((A), (B), (C), 0, 0, 0)
#else
__device__ __forceinline__ v4f mfma_k16_asm(v4s a, v4s b, v4f c) {
  asm volatile("v_mfma_f32_16x16x16_bf16 %0, %1, %2, %0" : "+v"(c) : "v"(a), "v"(b));
  return c;
}
#define MFMA_K16(A, B, C) mfma_k16_asm((A), (B), (C))
#endif

// ---------- cast hidden fp32 -> bf16 ----------
__global__ void cast_h_kernel(const float4* __restrict__ in, ushort4* __restrict__ out, int n4) {
  int i = blockIdx.x * blockDim.x + threadIdx.x;
  if (i < n4) {
    float4 v = in[i];
    ushort4 o;
    o.x = bfr(v.x); o.y = bfr(v.y); o.z = bfr(v.z); o.w = bfr(v.w);
    out[i] = o;
  }
}

// ---------- transpose-cast 4 weights [1024 x 1024] f32 -> Wt [N x K] bf16 (z picks) ----------
__global__ void transpose_cast4_kernel(const float* __restrict__ W0, const float* __restrict__ W1,
                                       const float* __restrict__ W2, const float* __restrict__ W3,
                                       us* __restrict__ O0, us* __restrict__ O1,
                                       us* __restrict__ O2, us* __restrict__ O3) {
  __shared__ float tile[32][33];
  const int z = blockIdx.z;
  const float* in = (z == 0) ? W0 : (z == 1) ? W1 : (z == 2) ? W2 : W3;
  us* out = (z == 0) ? O0 : (z == 1) ? O1 : (z == 2) ? O2 : O3;
  const float scale = (z == 0) ? 0.125f : 1.0f;  // fold attention SCALE into Wq
  const int N = 1024, K = 1024;
  int n0 = blockIdx.x * 32, k0 = blockIdx.y * 32;
  int tx = threadIdx.x, ty = threadIdx.y;
#pragma unroll
  for (int j = 0; j < 32; j += 8)
    tile[ty + j][tx] = in[(size_t)(k0 + ty + j) * N + n0 + tx];
  __syncthreads();
#pragma unroll
  for (int j = 0; j < 32; j += 8)
    out[(size_t)(n0 + ty + j) * K + k0 + tx] = bfr(tile[tx][ty + j] * scale);
}

// ---------- transpose V [bh][2048][64] -> Vt [bh][64][2048'] with per-32 kv permutation ----------
// kv' = (kv&~31) | quad*8 + h*4 + j  where quad=(kv>>2)&3, h=(kv>>4)&1, j=kv&3.
// This makes the flash PV A-fragments (K=16 mfma, k=quad*4+j) contiguous 16B per lane.
__global__ void transpose_v_kernel(const us* __restrict__ V, us* __restrict__ Vt) {
  __shared__ us t[64][65];
  int bh = blockIdx.y;
  int s0 = blockIdx.x * 64;
  const us* src = V + (size_t)bh * 2048 * 64;
  us* dst = Vt + (size_t)bh * 64 * 2048;
  int tx = threadIdx.x, ty = threadIdx.y;
#pragma unroll
  for (int j = 0; j < 64; j += 4)
    t[ty + j][tx] = src[(size_t)(s0 + ty + j) * 64 + tx];
  __syncthreads();
  int ptx = (tx & ~31) | (((tx >> 2) & 3) << 3) | (((tx >> 4) & 1) << 2) | (tx & 3);
#pragma unroll
  for (int j = 0; j < 64; j += 4)
    dst[(size_t)(ty + j) * 2048 + s0 + ptx] = t[tx][ty + j];
}

// ---------- GEMM: C[M x N] = A[M x 1024] @ Bt[N x 1024]^T  (bf16 in, fp32 acc) ----------
template <int EPI>
__global__ __launch_bounds__(256)
void gemm_bt_kernel(const us* __restrict__ A, const us* __restrict__ Bt,
                    us* __restrict__ qkv, float* __restrict__ outF,
                    const float* __restrict__ bias) {
  __shared__ __align__(16) us As[128 * 32];
  __shared__ __align__(16) us Bs[128 * 32];
  const int tid = threadIdx.x;
  const int wid = tid >> 6;
  const int lane = tid & 63;
  const int quad = lane >> 4;
  const int l16 = lane & 15;
  const int tile_m = blockIdx.y * 128;
  const int tile_n = blockIdx.x * 128;

  const int srow = wid * 32 + (lane >> 2);
  const int scol = (lane & 3) * 8;
  const us* ag = A + (size_t)(tile_m + srow) * 1024 + scol;
  const us* bg = Bt + (size_t)(tile_n + srow) * 1024 + scol;
  us* al = &As[srow * 32 + scol];
  us* bl = &Bs[srow * 32 + scol];

  v4f zero = {0.f, 0.f, 0.f, 0.f};
  v4f acc[4][4];
#pragma unroll
  for (int i = 0; i < 4; ++i)
#pragma unroll
    for (int j = 0; j < 4; ++j) acc[i][j] = zero;

  const int wm = (wid >> 1) * 64;
  const int wn = (wid & 1) * 64;

  for (int k0 = 0; k0 < 1024; k0 += 32) {
    async16(ag + k0, al);
    async16(ag + k0 + 16 * 1024, al + 16 * 32);
    async16(bg + k0, bl);
    async16(bg + k0 + 16 * 1024, bl + 16 * 32);
    __syncthreads();
    v8s a[4], b[4];
#pragma unroll
    for (int i = 0; i < 4; ++i)
      a[i] = *(const v8s*)&As[(wm + i * 16 + l16) * 32 + quad * 8];
#pragma unroll
    for (int j = 0; j < 4; ++j)
      b[j] = *(const v8s*)&Bs[(wn + j * 16 + l16) * 32 + quad * 8];
#pragma unroll
    for (int i = 0; i < 4; ++i)
#pragma unroll
      for (int j = 0; j < 4; ++j)
        acc[i][j] = __builtin_amdgcn_mfma_f32_16x16x32_bf16(a[i], b[j], acc[i][j], 0, 0, 0);
    __syncthreads();
  }

#pragma unroll
  for (int i = 0; i < 4; ++i)
#pragma unroll
    for (int j = 0; j < 4; ++j)
#pragma unroll
      for (int r = 0; r < 4; ++r) {
        int row = tile_m + wm + i * 16 + quad * 4 + r;
        int col = tile_n + wn + j * 16 + l16;
        float v = acc[i][j][r];
        if (EPI == 0) {
          int sel = col >> 10;
          int h = (col >> 6) & 15;
          int d = col & 63;
          int b_ = row >> 11;
          int s_ = row & 2047;
          qkv[(size_t)sel * 8388608 + (((size_t)(b_ * 16 + h) * 2048 + s_) * 64 + d)] = bfr(v);
        } else {
          outF[(size_t)row * 1024 + col] = v + bias[col];
        }
      }
}

// ---------- flash attention v2: S^T formulation, P stays in registers ----------
// S^T = K·Q^T  ->  C-layout (kv=quad*4+r, q=l16) == B-operand layout of K=16 mfma.
// O^T = V^T·P^T accumulated with mfma_f32_16x16x16_bf16; O^T transposed via LDS once at end.
// LDS = Ks 16K + Vts 16K = 32 KB; Q fragments in registers.
__global__ __launch_bounds__(256, 3)
void flash_kernel(const us* __restrict__ Q, const us* __restrict__ K,
                  const us* __restrict__ Vt, us* __restrict__ O) {
  __shared__ __align__(16) us Ks[128 * 64];   // reused as O-bounce in epilogue
  __shared__ __align__(16) us Vts[64 * 128];

  const int tid = threadIdx.x;
  const int wid = tid >> 6;
  const int lane = tid & 63;
  const int quad = lane >> 4;
  const int l16 = lane & 15;
  const int bh = blockIdx.y;
  const int q0 = blockIdx.x * 128;
  const int wq = wid * 32;
  const us* Qp = Q + (size_t)bh * (2048 * 64);
  const us* Kp = K + (size_t)bh * (2048 * 64);
  const us* Vp = Vt + (size_t)bh * (64 * 2048);

  // Q fragments (B-layout for QK^T): q = wq+mi*16+l16, k(d) = ks*32+quad*8+j. Loaded once.
  v8s qB[2][2];
#pragma unroll
  for (int mi = 0; mi < 2; ++mi)
#pragma unroll
    for (int ks = 0; ks < 2; ++ks)
      qB[mi][ks] = *(const v8s*)&Qp[(size_t)(q0 + wq + mi * 16 + l16) * 64 + ks * 32 + quad * 8];

  v4f zero = {0.f, 0.f, 0.f, 0.f};
  v4f o[4][2];  // O^T accumulators: [i = d-block][mi = q-block], (d=quad*4+r, q=l16)
#pragma unroll
  for (int i = 0; i < 4; ++i)
#pragma unroll
    for (int mi = 0; mi < 2; ++mi) o[i][mi] = zero;
  float m_st[2] = {-1e30f, -1e30f};
  float l_st[2] = {0.f, 0.f};

  for (int kv0 = 0; kv0 < 2048; kv0 += 128) {
    __syncthreads();  // all waves done reading previous tiles
    {  // stage K tile: 128 rows x 64 elems, 8-elem chunk swizzle c^(row&7)
      int r0 = wid * 32 + (lane >> 3);
      int c = lane & 7;
#pragma unroll
      for (int it = 0; it < 4; ++it) {
        int rr = r0 + it * 8;
        int cg = c ^ (rr & 7);
        async16(Kp + (size_t)(kv0 + rr) * 64 + cg * 8, &Ks[rr * 64 + c * 8]);
      }
    }
    {  // stage Vt tile: 64 rows (d) x 128 (kv'), 8-elem chunk swizzle c^(d&15)
      int d0 = wid * 16 + (lane >> 4);
      int c = lane & 15;
#pragma unroll
      for (int it = 0; it < 4; ++it) {
        int dd = d0 + it * 4;
        int cg = c ^ (dd & 15);
        async16(Vp + (size_t)dd * 2048 + kv0 + cg * 8, &Vts[dd * 128 + c * 8]);
      }
    }
    __syncthreads();

    // S^T = K·Q^T : sT[m][mi], kv = m*16+quad*4+r, q = l16 (+mi*16+wq)
    v4f sT[8][2];
#pragma unroll
    for (int m = 0; m < 8; ++m)
#pragma unroll
      for (int mi = 0; mi < 2; ++mi) sT[m][mi] = zero;
#pragma unroll
    for (int ks = 0; ks < 2; ++ks) {
      v8s kA[8];
#pragma unroll
      for (int m = 0; m < 8; ++m) {
        int kvr = m * 16 + l16;
        int cc = (ks * 4 + quad) ^ (kvr & 7);
        kA[m] = *(const v8s*)&Ks[kvr * 64 + cc * 8];
      }
#pragma unroll
      for (int m = 0; m < 8; ++m)
#pragma unroll
        for (int mi = 0; mi < 2; ++mi)
          sT[m][mi] = __builtin_amdgcn_mfma_f32_16x16x32_bf16(kA[m], qB[mi][ks], sT[m][mi], 0, 0, 0);
    }

    // online softmax: per-lane state (q = l16 is lane-uniform per mi)
    float mL[2];
#pragma unroll
    for (int mi = 0; mi < 2; ++mi) {
      float mx = sT[0][mi][0];
#pragma unroll
      for (int m = 0; m < 8; ++m)
#pragma unroll
        for (int r = 0; r < 4; ++r) mx = fmaxf(mx, sT[m][mi][r]);
      mx = fmaxf(mx, __shfl_xor(mx, 16));
      mx = fmaxf(mx, __shfl_xor(mx, 32));
      float mnew = fmaxf(m_st[mi], mx);
      float a = __builtin_amdgcn_exp2f((m_st[mi] - mnew) * LOG2E);
      m_st[mi] = mnew;
      mL[mi] = mnew * LOG2E;
      l_st[mi] *= a;
#pragma unroll
      for (int i = 0; i < 4; ++i) o[i][mi] = o[i][mi] * a;
    }

    // P^T built in registers (exp2 + round + perm-pack), fed straight into K=16 PV mfma
#pragma unroll
    for (int cp = 0; cp < 4; ++cp) {
      v4s bp[2][2];  // [dm = which 16-kv chunk of the pair][mi]
#pragma unroll
      for (int dm = 0; dm < 2; ++dm) {
        int m = cp * 2 + dm;
#pragma unroll
        for (int mi = 0; mi < 2; ++mi) {
          float p0 = __builtin_amdgcn_exp2f(sT[m][mi][0] * LOG2E - mL[mi]);
          float p1 = __builtin_amdgcn_exp2f(sT[m][mi][1] * LOG2E - mL[mi]);
          float p2 = __builtin_amdgcn_exp2f(sT[m][mi][2] * LOG2E - mL[mi]);
          float p3 = __builtin_amdgcn_exp2f(sT[m][mi][3] * LOG2E - mL[mi]);
          l_st[mi] += (p0 + p1) + (p2 + p3);
          u32 lo = __builtin_amdgcn_perm(f2u(p1) + 0x8000u, f2u(p0) + 0x8000u, 0x07060302u);
          u32 hi = __builtin_amdgcn_perm(f2u(p3) + 0x8000u, f2u(p2) + 0x8000u, 0x07060302u);
          union { u32 w[2]; v4s s; } u;
          u.w[0] = lo; u.w[1] = hi;
          bp[dm][mi] = u.s;
        }
      }
#pragma unroll
      for (int i = 0; i < 4; ++i) {
        int d = i * 16 + l16;
        int cc = (cp * 4 + quad) ^ l16;
        v8s vt = *(const v8s*)&Vts[d * 128 + cc * 8];  // both chunk-frags, pre-permuted layout
        v4s vlo = __builtin_shufflevector(vt, vt, 0, 1, 2, 3);
        v4s vhi = __builtin_shufflevector(vt, vt, 4, 5, 6, 7);
#pragma unroll
        for (int mi = 0; mi < 2; ++mi) {
          o[i][mi] = MFMA_K16(vlo, bp[0][mi], o[i][mi]);
          o[i][mi] = MFMA_K16(vhi, bp[1][mi], o[i][mi]);
        }
      }
    }
  }

  // finalize l (reduce across quads), then 1/l
#pragma unroll
  for (int mi = 0; mi < 2; ++mi) {
    float l = l_st[mi];
    l += __shfl_xor(l, 16);
    l += __shfl_xor(l, 32);
    l_st[mi] = 1.0f / l;
  }

  __syncthreads();  // all waves done with Ks of the last tile
  // O^T -> bounce (reuse Ks): layout [q 128][d 64], 8-elem chunks swizzled ^(q&7)
#pragma unroll
  for (int mi = 0; mi < 2; ++mi) {
    int q = wq + mi * 16 + l16;
#pragma unroll
    for (int i = 0; i < 4; ++i)
#pragma unroll
      for (int rp = 0; rp < 4; rp += 2) {
        int d = i * 16 + quad * 4 + rp;
        u32 w0 = f2u(o[i][mi][rp] * l_st[mi]) + 0x8000u;
        u32 w1 = f2u(o[i][mi][rp + 1] * l_st[mi]) + 0x8000u;
        u32 pk = __builtin_amdgcn_perm(w1, w0, 0x07060302u);
        *(u32*)&Ks[q * 64 + ((d >> 3) ^ (q & 7)) * 8 + (d & 7)] = pk;
      }
  }
  __syncthreads();
  const int b_ = bh >> 4, h_ = bh & 15;
#pragma unroll
  for (int it = 0; it < 4; ++it) {
    int u = it * 256 + tid;
    int row = u >> 3, ch = u & 7;
    v8s val = *(const v8s*)&Ks[row * 64 + (ch ^ (row & 7)) * 8];
    *(v8s*)&O[((size_t)(b_ * 2048 + q0 + row)) * 1024 + h_ * 64 + ch * 8] = val;
  }
}

// ---------- launch ----------
// ws layout (MiB offsets): 0 Hb(16, aliased by Ob) | 16 Wqt(2) | 18 Wkt(2) | 20 Wvt(2)
//                          | 22 Wot(2) | 24 Qb(16) | 40 Kb(16) | 56 Vb(16) | 72 Vtb(16)
extern "C" void kernel_launch(void* const* d_in, const int* in_sizes, int n_in,
                              void* d_out, int out_size, void* d_ws, size_t ws_size,
                              hipStream_t stream) {
  const float* Hs = (const float*)d_in[0];
  const float* Wq = (const float*)d_in[1];
  const float* Wk = (const float*)d_in[2];
  const float* Wv = (const float*)d_in[3];
  const float* Wo = (const float*)d_in[4];
  const float* bo = (const float*)d_in[5];
  float* out = (float*)d_out;
  char* ws = (char*)d_ws;
  const size_t MiB = 1ull << 20;
  us* Hb  = (us*)(ws);
  us* Wqt = (us*)(ws + 16 * MiB);
  us* Wkt = (us*)(ws + 18 * MiB);
  us* Wvt = (us*)(ws + 20 * MiB);
  us* Wot = (us*)(ws + 22 * MiB);
  us* Qb  = (us*)(ws + 24 * MiB);
  us* Kb  = (us*)(ws + 40 * MiB);
  us* Vb  = (us*)(ws + 56 * MiB);
  us* Vtb = (us*)(ws + 72 * MiB);
  us* Ob  = Hb;  // alias: Hb dead after QKV GEMM

  cast_h_kernel<<<8192, 256, 0, stream>>>((const float4*)Hs, (ushort4*)Hb, 2097152);
  transpose_cast4_kernel<<<dim3(32, 32, 4), dim3(32, 8), 0, stream>>>(Wq, Wk, Wv, Wo,
                                                                      Wqt, Wkt, Wvt, Wot);
  // fused QKV GEMM: Bt = [Wqt|Wkt|Wvt] contiguous => N = 3072
  gemm_bt_kernel<0><<<dim3(24, 64), 256, 0, stream>>>(Hb, Wqt, Qb, nullptr, nullptr);
  transpose_v_kernel<<<dim3(32, 64), dim3(64, 4), 0, stream>>>(Vb, Vtb);
  flash_kernel<<<dim3(16, 64), 256, 0, stream>>>(Qb, Kb, Vtb, Ob);
  gemm_bt_kernel<1><<<dim3(8, 64), 256, 0, stream>>>(Ob, Wot, nullptr, out, bo);
}

// Round 3
// 306.640 us; speedup vs baseline: 1.2790x; 1.2790x over previous
//
#include <hip/hip_runtime.h>
#include <stdint.h>

typedef short v8s __attribute__((ext_vector_type(8)));
typedef short v4s __attribute__((ext_vector_type(4)));
typedef float v4f __attribute__((ext_vector_type(4)));
typedef unsigned int u32;
typedef unsigned short us;

#define LOG2E 1.44269504088896340736f

__device__ __forceinline__ u32 f2u(float x) {
  union { float f; u32 u; } t; t.f = x; return t.u;
}

__device__ __forceinline__ unsigned short bfr(float x) {
  u32 u = f2u(x);
  u32 r = u + 0x7FFFu + ((u >> 16) & 1u);
  return (unsigned short)(r >> 16);
}

__device__ __forceinline__ void async16(const void* g, void* l) {
  __builtin_amdgcn_global_load_lds(
      (const __attribute__((address_space(1))) u32*)g,
      (__attribute__((address_space(3))) u32*)l, 16, 0, 0);
}

#if __has_builtin(__builtin_amdgcn_mfma_f32_16x16x16bf16_1k)
#define MFMA_K16(A, B, C) __builtin_amdgcn_mfma_f32_16x16x16bf16_1k((A), (B), (C), 0, 0, 0)
#elif __has_builtin(__builtin_amdgcn_mfma_f32_16x16x16_bf16)
#define MFMA_K16(A, B, C) __builtin_amdgcn_mfma_f32_16x16x16_bf16((A), (B), (C), 0, 0, 0)
#else
__device__ __forceinline__ v4f mfma_k16_asm(v4s a, v4s b, v4f c) {
  asm volatile("v_mfma_f32_16x16x16_bf16 %0, %1, %2, %0" : "+v"(c) : "v"(a), "v"(b));
  return c;
}
#define MFMA_K16(A, B, C) mfma_k16_asm((A), (B), (C))
#endif

// ---------- cast hidden fp32 -> bf16 ----------
__global__ void cast_h_kernel(const float4* __restrict__ in, ushort4* __restrict__ out, int n4) {
  int i = blockIdx.x * blockDim.x + threadIdx.x;
  if (i < n4) {
    float4 v = in[i];
    ushort4 o;
    o.x = bfr(v.x); o.y = bfr(v.y); o.z = bfr(v.z); o.w = bfr(v.w);
    out[i] = o;
  }
}

// ---------- transpose-cast 4 weights [1024 x 1024] f32 -> Wt [N x K] bf16 (z picks) ----------
__global__ void transpose_cast4_kernel(const float* __restrict__ W0, const float* __restrict__ W1,
                                       const float* __restrict__ W2, const float* __restrict__ W3,
                                       us* __restrict__ O0, us* __restrict__ O1,
                                       us* __restrict__ O2, us* __restrict__ O3) {
  __shared__ float tile[32][33];
  const int z = blockIdx.z;
  const float* in = (z == 0) ? W0 : (z == 1) ? W1 : (z == 2) ? W2 : W3;
  us* out = (z == 0) ? O0 : (z == 1) ? O1 : (z == 2) ? O2 : O3;
  const float scale = (z == 0) ? 0.125f : 1.0f;  // fold attention SCALE into Wq
  const int N = 1024, K = 1024;
  int n0 = blockIdx.x * 32, k0 = blockIdx.y * 32;
  int tx = threadIdx.x, ty = threadIdx.y;
#pragma unroll
  for (int j = 0; j < 32; j += 8)
    tile[ty + j][tx] = in[(size_t)(k0 + ty + j) * N + n0 + tx];
  __syncthreads();
#pragma unroll
  for (int j = 0; j < 32; j += 8)
    out[(size_t)(n0 + ty + j) * K + k0 + tx] = bfr(tile[tx][ty + j] * scale);
}

// ---------- transpose V [bh][2048][64] -> Vt [bh][64][2048'] with per-32 kv permutation ----------
// kv' = (kv&~31) | quad*8 + h*4 + j  where quad=(kv>>2)&3, h=(kv>>4)&1, j=kv&3.
// Makes the flash PV A-fragments (K=16 mfma, k=quad*4+j) contiguous 16B per lane.
__global__ void transpose_v_kernel(const us* __restrict__ V, us* __restrict__ Vt) {
  __shared__ us t[64][65];
  int bh = blockIdx.y;
  int s0 = blockIdx.x * 64;
  const us* src = V + (size_t)bh * 2048 * 64;
  us* dst = Vt + (size_t)bh * 64 * 2048;
  int tx = threadIdx.x, ty = threadIdx.y;
#pragma unroll
  for (int j = 0; j < 64; j += 4)
    t[ty + j][tx] = src[(size_t)(s0 + ty + j) * 64 + tx];
  __syncthreads();
  int ptx = (tx & ~31) | (((tx >> 2) & 3) << 3) | (((tx >> 4) & 1) << 2) | (tx & 3);
#pragma unroll
  for (int j = 0; j < 64; j += 4)
    dst[(size_t)(ty + j) * 2048 + s0 + ptx] = t[tx][ty + j];
}

// ---------- GEMM: C[M x N] = A[M x 1024] @ Bt[N x 1024]^T  (bf16 in, fp32 acc) ----------
template <int EPI>
__global__ __launch_bounds__(256)
void gemm_bt_kernel(const us* __restrict__ A, const us* __restrict__ Bt,
                    us* __restrict__ qkv, float* __restrict__ outF,
                    const float* __restrict__ bias) {
  __shared__ __align__(16) us As[128 * 32];
  __shared__ __align__(16) us Bs[128 * 32];
  const int tid = threadIdx.x;
  const int wid = tid >> 6;
  const int lane = tid & 63;
  const int quad = lane >> 4;
  const int l16 = lane & 15;
  const int tile_m = blockIdx.y * 128;
  const int tile_n = blockIdx.x * 128;

  const int srow = wid * 32 + (lane >> 2);
  const int scol = (lane & 3) * 8;
  const us* ag = A + (size_t)(tile_m + srow) * 1024 + scol;
  const us* bg = Bt + (size_t)(tile_n + srow) * 1024 + scol;
  us* al = &As[srow * 32 + scol];
  us* bl = &Bs[srow * 32 + scol];

  v4f zero = {0.f, 0.f, 0.f, 0.f};
  v4f acc[4][4];
#pragma unroll
  for (int i = 0; i < 4; ++i)
#pragma unroll
    for (int j = 0; j < 4; ++j) acc[i][j] = zero;

  const int wm = (wid >> 1) * 64;
  const int wn = (wid & 1) * 64;

  for (int k0 = 0; k0 < 1024; k0 += 32) {
    async16(ag + k0, al);
    async16(ag + k0 + 16 * 1024, al + 16 * 32);
    async16(bg + k0, bl);
    async16(bg + k0 + 16 * 1024, bl + 16 * 32);
    __syncthreads();
    v8s a[4], b[4];
#pragma unroll
    for (int i = 0; i < 4; ++i)
      a[i] = *(const v8s*)&As[(wm + i * 16 + l16) * 32 + quad * 8];
#pragma unroll
    for (int j = 0; j < 4; ++j)
      b[j] = *(const v8s*)&Bs[(wn + j * 16 + l16) * 32 + quad * 8];
#pragma unroll
    for (int i = 0; i < 4; ++i)
#pragma unroll
      for (int j = 0; j < 4; ++j)
        acc[i][j] = __builtin_amdgcn_mfma_f32_16x16x32_bf16(a[i], b[j], acc[i][j], 0, 0, 0);
    __syncthreads();
  }

#pragma unroll
  for (int i = 0; i < 4; ++i)
#pragma unroll
    for (int j = 0; j < 4; ++j)
#pragma unroll
      for (int r = 0; r < 4; ++r) {
        int row = tile_m + wm + i * 16 + quad * 4 + r;
        int col = tile_n + wn + j * 16 + l16;
        float v = acc[i][j][r];
        if (EPI == 0) {
          int sel = col >> 10;
          int h = (col >> 6) & 15;
          int d = col & 63;
          int b_ = row >> 11;
          int s_ = row & 2047;
          qkv[(size_t)sel * 8388608 + (((size_t)(b_ * 16 + h) * 2048 + s_) * 64 + d)] = bfr(v);
        } else {
          outF[(size_t)row * 1024 + col] = v + bias[col];
        }
      }
}

// ---------- flash attention v3: S^T formulation, P in registers, kv split in 64-halves ----------
// S^T = K·Q^T -> C-layout (kv=quad*4+r, q=l16) == B-operand layout of K=16 mfma, so P^T
// feeds O^T = V^T·P^T straight from registers. Each staged 128-kv tile is computed in two
// 64-kv halves so only sT[4][2] (32 regs) is live -> no spills under the (256,3) reg cap.
// LDS = Ks 16K + Vts 16K = 32 KB.
__global__ __launch_bounds__(256, 3)
void flash_kernel(const us* __restrict__ Q, const us* __restrict__ K,
                  const us* __restrict__ Vt, us* __restrict__ O) {
  __shared__ __align__(16) us Ks[128 * 64];   // reused as O-bounce in epilogue
  __shared__ __align__(16) us Vts[64 * 128];

  const int tid = threadIdx.x;
  const int wid = tid >> 6;
  const int lane = tid & 63;
  const int quad = lane >> 4;
  const int l16 = lane & 15;
  const int bh = blockIdx.y;
  const int q0 = blockIdx.x * 128;
  const int wq = wid * 32;
  const us* Qp = Q + (size_t)bh * (2048 * 64);
  const us* Kp = K + (size_t)bh * (2048 * 64);
  const us* Vp = Vt + (size_t)bh * (64 * 2048);

  // Q fragments (B-layout for QK^T): q = wq+mi*16+l16, k(d) = ks*32+quad*8+j. Loaded once.
  v8s qB[2][2];
#pragma unroll
  for (int mi = 0; mi < 2; ++mi)
#pragma unroll
    for (int ks = 0; ks < 2; ++ks)
      qB[mi][ks] = *(const v8s*)&Qp[(size_t)(q0 + wq + mi * 16 + l16) * 64 + ks * 32 + quad * 8];

  v4f zero = {0.f, 0.f, 0.f, 0.f};
  v4f o[4][2];  // O^T accumulators: [i = d-block][mi = q-block], (d=quad*4+r, q=l16)
#pragma unroll
  for (int i = 0; i < 4; ++i)
#pragma unroll
    for (int mi = 0; mi < 2; ++mi) o[i][mi] = zero;
  float m_st[2] = {-1e30f, -1e30f};
  float l_st[2] = {0.f, 0.f};

  for (int kv0 = 0; kv0 < 2048; kv0 += 128) {
    __syncthreads();  // all waves done reading previous tiles
    {  // stage K tile: 128 rows x 64 elems, 8-elem chunk swizzle c^(row&7)
      int r0 = wid * 32 + (lane >> 3);
      int c = lane & 7;
#pragma unroll
      for (int it = 0; it < 4; ++it) {
        int rr = r0 + it * 8;
        int cg = c ^ (rr & 7);
        async16(Kp + (size_t)(kv0 + rr) * 64 + cg * 8, &Ks[rr * 64 + c * 8]);
      }
    }
    {  // stage Vt tile: 64 rows (d) x 128 (kv'), 8-elem chunk swizzle c^(d&15)
      int d0 = wid * 16 + (lane >> 4);
      int c = lane & 15;
#pragma unroll
      for (int it = 0; it < 4; ++it) {
        int dd = d0 + it * 4;
        int cg = c ^ (dd & 15);
        async16(Vp + (size_t)dd * 2048 + kv0 + cg * 8, &Vts[dd * 128 + c * 8]);
      }
    }
    __syncthreads();

#pragma unroll
    for (int hf = 0; hf < 2; ++hf) {
      // S^T = K·Q^T for this 64-kv half: sT[m][mi], kv = hf*64 + m*16+quad*4+r, q = l16
      v4f sT[4][2];
#pragma unroll
      for (int m = 0; m < 4; ++m)
#pragma unroll
        for (int mi = 0; mi < 2; ++mi) sT[m][mi] = zero;
#pragma unroll
      for (int ks = 0; ks < 2; ++ks) {
        v8s kA[4];
#pragma unroll
        for (int m = 0; m < 4; ++m) {
          int kvr = hf * 64 + m * 16 + l16;
          int cc = (ks * 4 + quad) ^ (l16 & 7);
          kA[m] = *(const v8s*)&Ks[kvr * 64 + cc * 8];
        }
#pragma unroll
        for (int m = 0; m < 4; ++m)
#pragma unroll
          for (int mi = 0; mi < 2; ++mi)
            sT[m][mi] = __builtin_amdgcn_mfma_f32_16x16x32_bf16(kA[m], qB[mi][ks], sT[m][mi], 0, 0, 0);
      }

      // online softmax update (per-lane state; q = l16 lane-uniform per mi)
      float mL[2];
#pragma unroll
      for (int mi = 0; mi < 2; ++mi) {
        float mx = sT[0][mi][0];
#pragma unroll
        for (int m = 0; m < 4; ++m)
#pragma unroll
          for (int r = 0; r < 4; ++r) mx = fmaxf(mx, sT[m][mi][r]);
        mx = fmaxf(mx, __shfl_xor(mx, 16));
        mx = fmaxf(mx, __shfl_xor(mx, 32));
        float mnew = fmaxf(m_st[mi], mx);
        float a = __builtin_amdgcn_exp2f((m_st[mi] - mnew) * LOG2E);
        m_st[mi] = mnew;
        mL[mi] = mnew * LOG2E;
        l_st[mi] *= a;
#pragma unroll
        for (int i = 0; i < 4; ++i) o[i][mi] = o[i][mi] * a;
      }

      // P^T built in registers (exp2 + round + perm-pack), fed straight into K=16 PV mfma
#pragma unroll
      for (int cp = 0; cp < 2; ++cp) {
        v4s bp[2][2];  // [dm = 16-kv chunk within the 32-group][mi]
#pragma unroll
        for (int dm = 0; dm < 2; ++dm) {
          int m = cp * 2 + dm;
#pragma unroll
          for (int mi = 0; mi < 2; ++mi) {
            float p0 = __builtin_amdgcn_exp2f(sT[m][mi][0] * LOG2E - mL[mi]);
            float p1 = __builtin_amdgcn_exp2f(sT[m][mi][1] * LOG2E - mL[mi]);
            float p2 = __builtin_amdgcn_exp2f(sT[m][mi][2] * LOG2E - mL[mi]);
            float p3 = __builtin_amdgcn_exp2f(sT[m][mi][3] * LOG2E - mL[mi]);
            l_st[mi] += (p0 + p1) + (p2 + p3);
            u32 lo = __builtin_amdgcn_perm(f2u(p1) + 0x8000u, f2u(p0) + 0x8000u, 0x07060302u);
            u32 hi = __builtin_amdgcn_perm(f2u(p3) + 0x8000u, f2u(p2) + 0x8000u, 0x07060302u);
            union { u32 w[2]; v4s s; } u;
            u.w[0] = lo; u.w[1] = hi;
            bp[dm][mi] = u.s;
          }
        }
#pragma unroll
        for (int i = 0; i < 4; ++i) {
          int d = i * 16 + l16;
          int cc = (hf * 8 + cp * 4 + quad) ^ l16;
          v8s vt = *(const v8s*)&Vts[d * 128 + cc * 8];  // pre-permuted: both 16-kv frags
          v4s vlo = __builtin_shufflevector(vt, vt, 0, 1, 2, 3);
          v4s vhi = __builtin_shufflevector(vt, vt, 4, 5, 6, 7);
#pragma unroll
          for (int mi = 0; mi < 2; ++mi) {
            o[i][mi] = MFMA_K16(vlo, bp[0][mi], o[i][mi]);
            o[i][mi] = MFMA_K16(vhi, bp[1][mi], o[i][mi]);
          }
        }
      }
    }
  }

  // finalize l (reduce across quads), then 1/l
#pragma unroll
  for (int mi = 0; mi < 2; ++mi) {
    float l = l_st[mi];
    l += __shfl_xor(l, 16);
    l += __shfl_xor(l, 32);
    l_st[mi] = 1.0f / l;
  }

  __syncthreads();  // all waves done with Ks of the last tile
  // O^T -> bounce (reuse Ks): layout [q 128][d 64], 8-elem chunks swizzled ^(q&7)
#pragma unroll
  for (int mi = 0; mi < 2; ++mi) {
    int q = wq + mi * 16 + l16;
#pragma unroll
    for (int i = 0; i < 4; ++i)
#pragma unroll
      for (int rp = 0; rp < 4; rp += 2) {
        int d = i * 16 + quad * 4 + rp;
        u32 w0 = f2u(o[i][mi][rp] * l_st[mi]) + 0x8000u;
        u32 w1 = f2u(o[i][mi][rp + 1] * l_st[mi]) + 0x8000u;
        u32 pk = __builtin_amdgcn_perm(w1, w0, 0x07060302u);
        *(u32*)&Ks[q * 64 + ((d >> 3) ^ (q & 7)) * 8 + (d & 7)] = pk;
      }
  }
  __syncthreads();
  const int b_ = bh >> 4, h_ = bh & 15;
#pragma unroll
  for (int it = 0; it < 4; ++it) {
    int u = it * 256 + tid;
    int row = u >> 3, ch = u & 7;
    v8s val = *(const v8s*)&Ks[row * 64 + (ch ^ (row & 7)) * 8];
    *(v8s*)&O[((size_t)(b_ * 2048 + q0 + row)) * 1024 + h_ * 64 + ch * 8] = val;
  }
}

// ---------- launch ----------
// ws layout (MiB offsets): 0 Hb(16, aliased by Ob) | 16 Wqt(2) | 18 Wkt(2) | 20 Wvt(2)
//                          | 22 Wot(2) | 24 Qb(16) | 40 Kb(16) | 56 Vb(16) | 72 Vtb(16)
extern "C" void kernel_launch(void* const* d_in, const int* in_sizes, int n_in,
                              void* d_out, int out_size, void* d_ws, size_t ws_size,
                              hipStream_t stream) {
  const float* Hs = (const float*)d_in[0];
  const float* Wq = (const float*)d_in[1];
  const float* Wk = (const float*)d_in[2];
  const float* Wv = (const float*)d_in[3];
  const float* Wo = (const float*)d_in[4];
  const float* bo = (const float*)d_in[5];
  float* out = (float*)d_out;
  char* ws = (char*)d_ws;
  const size_t MiB = 1ull << 20;
  us* Hb  = (us*)(ws);
  us* Wqt = (us*)(ws + 16 * MiB);
  us* Wkt = (us*)(ws + 18 * MiB);
  us* Wvt = (us*)(ws + 20 * MiB);
  us* Wot = (us*)(ws + 22 * MiB);
  us* Qb  = (us*)(ws + 24 * MiB);
  us* Kb  = (us*)(ws + 40 * MiB);
  us* Vb  = (us*)(ws + 56 * MiB);
  us* Vtb = (us*)(ws + 72 * MiB);
  us* Ob  = Hb;  // alias: Hb dead after QKV GEMM

  cast_h_kernel<<<8192, 256, 0, stream>>>((const float4*)Hs, (ushort4*)Hb, 2097152);
  transpose_cast4_kernel<<<dim3(32, 32, 4), dim3(32, 8), 0, stream>>>(Wq, Wk, Wv, Wo,
                                                                      Wqt, Wkt, Wvt, Wot);
  // fused QKV GEMM: Bt = [Wqt|Wkt|Wvt] contiguous => N = 3072
  gemm_bt_kernel<0><<<dim3(24, 64), 256, 0, stream>>>(Hb, Wqt, Qb, nullptr, nullptr);
  transpose_v_kernel<<<dim3(32, 64), dim3(64, 4), 0, stream>>>(Vb, Vtb);
  flash_kernel<<<dim3(16, 64), 256, 0, stream>>>(Qb, Kb, Vtb, Ob);
  gemm_bt_kernel<1><<<dim3(8, 64), 256, 0, stream>>>(Ob, Wot, nullptr, out, bo);
}